// Round 7
// baseline (72.969 us; speedup 1.0000x reference)
//
#include <hip/hip_runtime.h>
#include <hip/hip_bf16.h>

#define WT0 (-0.09375f)
#define WT1 (0.59375f)

// ---------------------------------------------------------------------------
// Shared bilateral-loss tile core. Tile = (64*PX) x 4 pixels, 256 threads,
// PX px/thread, vector rw loads. sf/sh are LDS [8][TW+4] flat. Returns this
// thread's sum of squared normalized diffs.
// ---------------------------------------------------------------------------
template <int S, int PX>
__device__ __forceinline__ float bilat_tile(
    const float* __restrict__ Fb, const float* __restrict__ Hb,
    const float* __restrict__ rwB,           // rw + b*25*S*S
    float* __restrict__ sf, float* __restrict__ sh,
    const float* __restrict__ swin,
    int bx0, int by0, int tid)
{
    constexpr int TW = 64 * PX;
    constexpr int LW = TW + 4;
    const int tx = tid & 63, ty = tid >> 6;

    for (int i = tid; i < 8 * LW; i += 256) {
        const int r = i / LW, c = i % LW;
        const int y = by0 + r - 2, x = bx0 + c - 2;
        float fv = 0.f, hv = 0.f;
        if ((unsigned)y < (unsigned)S && (unsigned)x < (unsigned)S) {
            const size_t id = (size_t)y * S + x;
            fv = Fb[id]; hv = Hb[id];
        }
        sf[r * LW + c] = fv; sh[r * LW + c] = hv;
    }
    __syncthreads();

    const int x0 = bx0 + PX * tx, y = by0 + ty;
    const size_t ks = (size_t)S * S;
    const float* rwp = rwB + (size_t)y * S + x0;

    float wsum[PX], fs[PX], hs[PX];
#pragma unroll
    for (int p = 0; p < PX; ++p) { wsum[p] = 0.f; fs[p] = 0.f; hs[p] = 0.f; }

#pragma unroll
    for (int di = 0; di < 5; ++di) {
        float f9[PX + 4], h9[PX + 4];
#pragma unroll
        for (int j = 0; j < PX + 4; ++j) {
            f9[j] = sf[(ty + di) * LW + PX * tx + j];
            h9[j] = sh[(ty + di) * LW + PX * tx + j];
        }
#pragma unroll
        for (int dj = 0; dj < 5; ++dj) {
            const int k = di * 5 + dj;
            float rv[PX];
            if constexpr (PX == 4) {
                const float4 t4 = *(const float4*)(rwp + (size_t)k * ks);
                rv[0] = t4.x; rv[1] = t4.y; rv[2] = t4.z; rv[3] = t4.w;
            } else if constexpr (PX == 2) {
                const float2 t2 = *(const float2*)(rwp + (size_t)k * ks);
                rv[0] = t2.x; rv[1] = t2.y;
            } else {
                rv[0] = rwp[(size_t)k * ks];
            }
#pragma unroll
            for (int p = 0; p < PX; ++p) {
                const float wm = swin[k] * rv[p];
                wsum[p] += wm;
                fs[p] = fmaf(wm, f9[dj + p], fs[p]);
                hs[p] = fmaf(wm, h9[dj + p], hs[p]);
            }
        }
    }
    float v = 0.f;
#pragma unroll
    for (int p = 0; p < PX; ++p) {
        const float d = (fs[p] - hs[p]) / wsum[p];
        v = fmaf(d, d, v);
    }
    return v;
}

__device__ __forceinline__ void reduce_and_store(
    float v, float scale, int tid, float* wred, double* slot)
{
#pragma unroll
    for (int off = 32; off > 0; off >>= 1) v += __shfl_down(v, off, 64);
    if ((tid & 63) == 0) wred[tid >> 6] = v;
    __syncthreads();
    if (tid == 0) {
        const float s = wred[0] + wred[1] + wred[2] + wred[3];
        *slot = (double)s * (double)scale;
    }
}

// ---------------------------------------------------------------------------
// K1: 4096 blocks.
//   lin < 2048 : level-0 loss (tile 256x4, 4 px/thread, float4 rw0 loads).
//   lin >= 2048: pyramid block — builds the f1/f2/f3 cascade for a 32x32
//     region of the original image entirely in LDS (50x50 edge-clamped src
//     stage -> L1 24x24 -> L2 11x11 -> L3 4x4), writing interiors to global.
//     These reads are L2/L3-cached (fake/hdr also streamed by loss blocks),
//     so the pyramid hides inside the rw0 HBM stream.
// LDS: max(loss 16.6KB, pyr 25.6KB) -> 6 blocks/CU.
// ---------------------------------------------------------------------------
__global__ __launch_bounds__(256) void k1_kernel(
    const float* __restrict__ fake, const float* __restrict__ hdr,
    const float* __restrict__ window, const float* __restrict__ rw0,
    double* __restrict__ slots,
    float* __restrict__ f1, float* __restrict__ h1,
    float* __restrict__ f2, float* __restrict__ h2,
    float* __restrict__ f3, float* __restrict__ h3)
{
    __shared__ float smem[6400];
    __shared__ float swin[25];
    __shared__ float wred[4];

    const int tid = threadIdx.x;
    if (tid < 25) swin[tid] = window[tid];
    const int lin = blockIdx.x;

    if (lin < 2048) {
        const int b = lin >> 8, t = lin & 255;
        const int by0 = (t >> 1) * 4, bx0 = (t & 1) * 256;
        const float v = bilat_tile<512, 4>(
            fake + (size_t)b * 512 * 512, hdr + (size_t)b * 512 * 512,
            rw0 + (size_t)b * 25 * 512 * 512,
            smem, smem + 2080, swin, bx0, by0, tid);
        reduce_and_store(v, 1.0f / (8.f * 512.f * 512.f), tid, wred, &slots[lin]);
        return;
    }

    // ---- pyramid branch ----
    const int p = lin - 2048;
    const int b = p >> 8, q = p & 255;
    const int Y = q >> 4, X = q & 15;
    float* s0  = smem;          // [2][50][50]
    float* l1t = smem + 5000;   // [2][24][24]
    float* l2t = smem + 6152;   // [2][11][11]
    const float* srcF = fake + (size_t)b * 512 * 512;
    const float* srcH = hdr  + (size_t)b * 512 * 512;
    const float wt[4] = {WT0, WT1, WT1, WT0};

    const int r0 = 32 * Y - 7, c0 = 32 * X - 7;   // src stage origin
    for (int i = tid; i < 2 * 50 * 50; i += 256) {
        const int img = i / 2500, j = i % 2500;
        const int r = j / 50, c = j % 50;
        const int gy = min(max(r0 + r, 0), 511);
        const int gx = min(max(c0 + c, 0), 511);
        s0[i] = (img ? srcH : srcF)[(size_t)gy * 512 + gx];
    }
    __syncthreads();

    // L1 (f1 coords), local entry (r,c) holds L1[clamp(r1+r)][clamp(c1+c)]
    const int r1 = 16 * Y - 3, c1 = 16 * X - 3;
    for (int i = tid; i < 2 * 24 * 24; i += 256) {
        const int img = i / 576, j = i % 576;
        const int r = j / 24, c = j % 24;
        const int g1y = min(max(r1 + r, 0), 255);
        const int g1x = min(max(c1 + c, 0), 255);
        int sy[4], sx[4];
#pragma unroll
        for (int k = 0; k < 4; ++k) {
            sy[k] = min(max(2 * g1y - 1 + k, 0), 511) - r0;
            sx[k] = min(max(2 * g1x - 1 + k, 0), 511) - c0;
        }
        float a = 0.f;
#pragma unroll
        for (int ky = 0; ky < 4; ++ky) {
            const float* row = s0 + img * 2500 + sy[ky] * 50;
            const float rs = WT0 * (row[sx[0]] + row[sx[3]]) + WT1 * (row[sx[1]] + row[sx[2]]);
            a = fmaf(wt[ky], rs, a);
        }
        l1t[i] = a;
        if (r >= 3 && r < 19 && c >= 3 && c < 19) {
            float* dst = img ? h1 : f1;
            dst[((size_t)b * 256 + (r1 + r)) * 256 + (c1 + c)] = a;
        }
    }
    __syncthreads();

    const int r2 = 8 * Y - 1, c2 = 8 * X - 1;
    for (int i = tid; i < 2 * 11 * 11; i += 256) {
        const int img = i / 121, j = i % 121;
        const int r = j / 11, c = j % 11;
        const int g2y = min(max(r2 + r, 0), 127);
        const int g2x = min(max(c2 + c, 0), 127);
        int sy[4], sx[4];
#pragma unroll
        for (int k = 0; k < 4; ++k) {
            sy[k] = min(max(2 * g2y - 1 + k, 0), 255) - r1;
            sx[k] = min(max(2 * g2x - 1 + k, 0), 255) - c1;
        }
        float a = 0.f;
#pragma unroll
        for (int ky = 0; ky < 4; ++ky) {
            const float* row = l1t + img * 576 + sy[ky] * 24;
            const float rs = WT0 * (row[sx[0]] + row[sx[3]]) + WT1 * (row[sx[1]] + row[sx[2]]);
            a = fmaf(wt[ky], rs, a);
        }
        l2t[i] = a;
        if (r >= 1 && r < 9 && c >= 1 && c < 9) {
            float* dst = img ? h2 : f2;
            dst[((size_t)b * 128 + (r2 + r)) * 128 + (c2 + c)] = a;
        }
    }
    __syncthreads();

    for (int i = tid; i < 2 * 4 * 4; i += 256) {
        const int img = i / 16, j = i % 16;
        const int r = j / 4, c = j % 4;
        const int g3y = 4 * Y + r, g3x = 4 * X + c;
        int sy[4], sx[4];
#pragma unroll
        for (int k = 0; k < 4; ++k) {
            sy[k] = min(max(2 * g3y - 1 + k, 0), 127) - r2;
            sx[k] = min(max(2 * g3x - 1 + k, 0), 127) - c2;
        }
        float a = 0.f;
#pragma unroll
        for (int ky = 0; ky < 4; ++ky) {
            const float* row = l2t + img * 121 + sy[ky] * 11;
            const float rs = WT0 * (row[sx[0]] + row[sx[3]]) + WT1 * (row[sx[1]] + row[sx[2]]);
            a = fmaf(wt[ky], rs, a);
        }
        float* dst = img ? h3 : f3;
        dst[((size_t)b * 64 + g3y) * 64 + g3x] = a;
    }
}

// ---------------------------------------------------------------------------
// K2: levels 1+2+3 loss in one launch (896 blocks), all reading materialized
// pyramid images. LDS 16.6KB -> 9 blocks/CU; everything streams concurrently.
// ---------------------------------------------------------------------------
__global__ __launch_bounds__(256) void k2_kernel(
    const float* __restrict__ window,
    const float* __restrict__ rw1, const float* __restrict__ rw2,
    const float* __restrict__ rw3,
    const float* __restrict__ f1, const float* __restrict__ h1,
    const float* __restrict__ f2, const float* __restrict__ h2,
    const float* __restrict__ f3, const float* __restrict__ h3,
    double* __restrict__ slots)
{
    __shared__ float smem[4160];
    __shared__ float swin[25];
    __shared__ float wred[4];

    const int tid = threadIdx.x;
    if (tid < 25) swin[tid] = window[tid];
    const int lin = blockIdx.x;

    float v, scale;
    if (lin < 512) {
        const int b = lin >> 6, by0 = (lin & 63) * 4;
        v = bilat_tile<256, 4>(
            f1 + (size_t)b * 65536, h1 + (size_t)b * 65536,
            rw1 + (size_t)b * 25 * 65536,
            smem, smem + 2080, swin, 0, by0, tid);
        scale = 0.5f / (8.f * 256.f * 256.f);
    } else if (lin < 768) {
        const int t = lin - 512, b = t >> 5, by0 = (t & 31) * 4;
        v = bilat_tile<128, 2>(
            f2 + (size_t)b * 16384, h2 + (size_t)b * 16384,
            rw2 + (size_t)b * 25 * 16384,
            smem, smem + 1056, swin, 0, by0, tid);
        scale = 0.25f / (8.f * 128.f * 128.f);
    } else {
        const int t = lin - 768, b = t >> 4, by0 = (t & 15) * 4;
        v = bilat_tile<64, 1>(
            f3 + (size_t)b * 4096, h3 + (size_t)b * 4096,
            rw3 + (size_t)b * 25 * 4096,
            smem, smem + 544, swin, 0, by0, tid);
        scale = 0.125f / (8.f * 64.f * 64.f);
    }
    reduce_and_store(v, scale, tid, wred, &slots[2048 + lin]);
}

__global__ void finalize_kernel(const double* __restrict__ slots, float* __restrict__ out, int n)
{
    __shared__ double dred[4];
    const int t = threadIdx.x;  // 256 threads
    double s = 0.0;
    for (int i = t; i < n; i += 256) s += slots[i];
#pragma unroll
    for (int off = 32; off > 0; off >>= 1) s += __shfl_down(s, off, 64);
    if ((t & 63) == 0) dred[t >> 6] = s;
    __syncthreads();
    if (t == 0) out[0] = (float)(dred[0] + dred[1] + dred[2] + dred[3]);
}

extern "C" void kernel_launch(void* const* d_in, const int* in_sizes, int n_in,
                              void* d_out, int out_size, void* d_ws, size_t ws_size,
                              hipStream_t stream)
{
    const float* fake   = (const float*)d_in[0];
    const float* hdr    = (const float*)d_in[1];
    const float* window = (const float*)d_in[2];
    const float* rw0    = (const float*)d_in[3];
    const float* rw1    = (const float*)d_in[4];
    const float* rw2    = (const float*)d_in[5];
    const float* rw3    = (const float*)d_in[6];
    float* out = (float*)d_out;

    const int B = 8;
    char* ws = (char*)d_ws;
    double* slots = (double*)ws;                 // 2944 doubles, all stored
    float* f1 = (float*)(ws + 32768);
    const size_t n1 = (size_t)B * 256 * 256;
    float* h1 = f1 + n1;
    float* f2 = h1 + n1;
    const size_t n2 = (size_t)B * 128 * 128;
    float* h2 = f2 + n2;
    float* f3 = h2 + n2;
    const size_t n3 = (size_t)B * 64 * 64;
    float* h3 = f3 + n3;

    // K1: level-0 loss (2048 blocks) + full pyramid build (2048 blocks).
    k1_kernel<<<dim3(4096), 256, 0, stream>>>(
        fake, hdr, window, rw0, slots, f1, h1, f2, h2, f3, h3);

    // K2: levels 1+2+3 loss concurrently (512+256+128 blocks).
    k2_kernel<<<dim3(896), 256, 0, stream>>>(
        window, rw1, rw2, rw3, f1, h1, f2, h2, f3, h3, slots);

    // K3: final reduction of 2944 slots.
    finalize_kernel<<<1, 256, 0, stream>>>(slots, out, 2944);
}